// Round 6
// baseline (788.674 us; speedup 1.0000x reference)
//
#include <hip/hip_runtime.h>

namespace {

constexpr int D  = 64;    // channels per head
constexpr int T  = 2048;  // sequence length
constexpr int NT = T / 64;
constexpr float SCL = 0.125f * 1.44269504088896340736f;  // scale^2 * log2(e)

// workspace layout (units: unsigned short):
//  [0, 64*32*8192)             KV tiles: (h*32+kt)*8192
//     K: first 4096 shorts, [s][c] rows of 64, granule-swizzled (16-row quarter = contiguous 2 KB)
//     V: next 4096 shorts, QUARTER-BLOCKED: quarter q (2 KB) = rows c of 16 s, granules of 4 shorts swizzled g^((c>>2)&3)
//  [QP_OFF, ...)               Q tiles: (h*32+qt64)*4096 swizzled [t][c], PRE-SCALED by SCL
constexpr size_t QP_OFF  = (size_t)64 * 32 * 8192;
constexpr size_t WS_NEED = ((size_t)64 * 32 * 8192 + (size_t)64 * 32 * 4096) * 2;  // 50331648 B

typedef __bf16 bf16x8 __attribute__((ext_vector_type(8)));
typedef float  f32x4  __attribute__((ext_vector_type(4)));
typedef unsigned short u16x4 __attribute__((ext_vector_type(4)));
typedef unsigned short u16x8 __attribute__((ext_vector_type(8)));
typedef unsigned int   u32x2 __attribute__((ext_vector_type(2)));
typedef short          s16x4 __attribute__((ext_vector_type(4)));

__device__ inline unsigned short f2bf(float f) {   // RNE fp32->bf16, finite inputs
    unsigned int u = __builtin_bit_cast(unsigned int, f);
    u += 0x7FFFu + ((u >> 16) & 1u);
    return (unsigned short)(u >> 16);
}

__device__ inline unsigned int pkbf(float a, float b) {
#if __has_builtin(__builtin_amdgcn_cvt_pk_bf16_f32)
    auto r = __builtin_amdgcn_cvt_pk_bf16_f32(a, b);
    static_assert(sizeof(r) == 4, "cvt_pk_bf16 size");
    return __builtin_bit_cast(unsigned int, r);
#else
    return (unsigned int)f2bf(a) | ((unsigned int)f2bf(b) << 16);
#endif
}

// 64-short rows, 16B granules XOR-swizzled by ((row>>1)&7) (K/Q images).
__device__ inline int frag_off(int row, int c0) {
    int g = (c0 >> 3) ^ ((row >> 1) & 7);
    return row * 64 + g * 8;
}

__device__ inline void async_cp16(const void* g, void* l) {
    __builtin_amdgcn_global_load_lds(
        (const __attribute__((address_space(1))) unsigned int*)g,
        (__attribute__((address_space(3))) unsigned int*)l, 16, 0, 0);
}

// ---------------- pre-pass: fp32 -> bf16, swizzled tiles (exact R0) ----------
__global__ __launch_bounds__(256)
void prepass(const float* __restrict__ qkv, unsigned short* __restrict__ ws) {
    const int tile = blockIdx.x, h = blockIdx.y, z = blockIdx.z;
    const int tid = threadIdx.x;
    const float* src = qkv + (size_t)h * 3 * D * T + (size_t)z * D * T + tile * 64;
    __shared__ unsigned short L[4096];

    if (z == 2) {  // V: quarter-blocked [wq][c][16s], granule(4sh) swizzle g^((c>>2)&3)
        unsigned short* dst = ws + (size_t)(h * 32 + tile) * 8192 + 4096;
        const int c = tid >> 2, g = tid & 3;
        const int sg = g ^ ((c >> 2) & 3);           // source granule (s-local/4)
        #pragma unroll
        for (int wq = 0; wq < 4; wq++) {
            f32x4 a = *(const f32x4*)(src + (size_t)c * T + wq * 16 + sg * 4);
            u16x4 wv = { f2bf(a[0]), f2bf(a[1]), f2bf(a[2]), f2bf(a[3]) };
            *(u16x4*)(dst + wq * 1024 + tid * 4) = wv;   // coalesced 8B stores
        }
    } else {       // Q/K: transpose [c][t] -> swizzled [t][c] via LDS
        const float m = (z == 0) ? SCL : 1.0f;   // fold softmax scale into Q
        const int c0 = (tid >> 4) * 4, s4 = tid & 15;
        float fr[4][4];
        #pragma unroll
        for (int r = 0; r < 4; r++)
            *(f32x4*)fr[r] = *(const f32x4*)(src + (size_t)(c0 + r) * T + s4 * 4);
        #pragma unroll
        for (int j = 0; j < 4; j++) {
            int trow = s4 * 4 + j;
            u16x4 wv = { f2bf(fr[0][j] * m), f2bf(fr[1][j] * m),
                         f2bf(fr[2][j] * m), f2bf(fr[3][j] * m) };
            *(u16x4*)(L + frag_off(trow, c0) + (c0 & 7)) = wv;
        }
        __syncthreads();
        unsigned short* dst = (z == 0)
            ? ws + QP_OFF + (size_t)(h * 32 + tile) * 4096
            : ws + (size_t)(h * 32 + tile) * 8192;
        #pragma unroll
        for (int i = 0; i < 2; i++)
            *(u16x8*)(dst + tid * 16 + i * 8) = *(const u16x8*)(L + tid * 16 + i * 8);
    }
}

// ---------------- main: 8-wave s x t split flash attention -------------------
// Block = 512 threads = 8 waves; wave w = (sg = w>>2, ts = w&3).
// Wave owns t-rows {16ts..16ts+16} in BOTH 64-t halves (2 strips, amortizes
// K/V fragments like R5) but only s-quarters {2sg, 2sg+1} (halves per-wave
// DS traffic so total DS/CU is unchanged vs R5 at 2x the waves).
// 32 waves/CU potential (was 16): attacks the measured latency-bound
// plateau (R0/R4/R5 all ~105 us, no pipe >45%, occupancy stuck ~31%).
// O and l are s-partials: single 2-way LDS merge epilogue (sg1 -> sg0).
// Staging skeleton proven in R4/R5: shared 16KB tile dbuf, raw s_barrier
// pair, stage distance 2; 2 cps/thread -> steady-state vmcnt(2).

#define STAGE(J, B)                                                          \
  { const char* g = kvb + (size_t)(J) * 16384;                               \
    char* lk = lbase + (B) * 16384;                                          \
    async_cp16(g,        lk);                                                \
    async_cp16(g + 8192, lk + 8192); }

#define BODY(KT, B, DO_STAGE, WAITIMM)                                       \
  {                                                                          \
    __builtin_amdgcn_s_waitcnt(WAITIMM);  /* own tile-KT cps landed */       \
    __builtin_amdgcn_s_barrier();         /* ALL waves' tile-KT landed */    \
    __builtin_amdgcn_sched_barrier(0);    /* no ds_read hoists above */      \
    _Pragma("unroll")                                                        \
    for (int qq = 0; qq < 2; qq++) {      /* this group's 2 s-quarters */    \
      const char* kb = sbuf + (B) * 16384 + qBase + qq * 2048;               \
      const char* vb = kb + 8192;                                            \
      bf16x8 aK0 = *(const bf16x8*)(kb + aK0o);                              \
      bf16x8 aK1 = *(const bf16x8*)(kb + aK1o);                              \
      s16x4 aV0 = *(const s16x4*)(vb + aVo);                                 \
      s16x4 aV1 = *(const s16x4*)(vb + aVo + 512);                           \
      s16x4 aV2 = *(const s16x4*)(vb + aVo + 1024);                          \
      s16x4 aV3 = *(const s16x4*)(vb + aVo + 1536);                          \
      _Pragma("unroll")                                                      \
      for (int st = 0; st < 2; st++) {                                       \
        f32x4 s = __builtin_amdgcn_mfma_f32_16x16x32_bf16(                   \
            aK0, bQ[st][0], ZF, 0, 0, 0);                                    \
        s = __builtin_amdgcn_mfma_f32_16x16x32_bf16(aK1, bQ[st][1], s, 0,0,0);\
        float p0 = __builtin_amdgcn_exp2f(s[0]);                             \
        float p1 = __builtin_amdgcn_exp2f(s[1]);                             \
        float p2 = __builtin_amdgcn_exp2f(s[2]);                             \
        float p3 = __builtin_amdgcn_exp2f(s[3]);                             \
        l_acc[st] += (p0 + p1) + (p2 + p3);                                  \
        u32x2 pk = { pkbf(p0, p1), pkbf(p2, p3) };                           \
        s16x4 bP = __builtin_bit_cast(s16x4, pk);                            \
        acc_o[st][0] = __builtin_amdgcn_mfma_f32_16x16x16bf16_1k(            \
            aV0, bP, acc_o[st][0], 0, 0, 0);                                 \
        acc_o[st][1] = __builtin_amdgcn_mfma_f32_16x16x16bf16_1k(            \
            aV1, bP, acc_o[st][1], 0, 0, 0);                                 \
        acc_o[st][2] = __builtin_amdgcn_mfma_f32_16x16x16bf16_1k(            \
            aV2, bP, acc_o[st][2], 0, 0, 0);                                 \
        acc_o[st][3] = __builtin_amdgcn_mfma_f32_16x16x16bf16_1k(            \
            aV3, bP, acc_o[st][3], 0, 0, 0);                                 \
      }                                                                      \
    }                                                                        \
    if (DO_STAGE) {                                                          \
      __builtin_amdgcn_s_waitcnt(0xC07F);  /* lgkmcnt(0): reads done */      \
      __builtin_amdgcn_s_barrier();        /* buf (B) free to overwrite */   \
      STAGE((KT) + 2, B)                                                     \
    }                                                                        \
  }

__global__ __launch_bounds__(512, 6)
void attn_main(const unsigned short* __restrict__ ws, float* __restrict__ out) {
    const int h  = blockIdx.x;      // head pinned to XCD h%8 for L2 locality
    const int qt = blockIdx.y;      // 128-t Q-block
    const int t0 = qt * 128;
    const int tid  = threadIdx.x;
    const int lane = tid & 63;
    const int w    = tid >> 6;
    const int sg   = w >> 2;        // s-group: quarters {2sg, 2sg+1}
    const int ts   = w & 3;         // t-strip: rows 16ts..16ts+16 of each half
    const int ln   = lane & 15, q4 = lane >> 4;

    __shared__ char  sbuf[32768];   // 2 x 16KB shared KV staging (dbuf); merge scratch
    __shared__ float lmrg[128];     // sg1 l partials [ts*2+st][ln]
    char* lbase = sbuf + tid * 16;  // staging: thread copies [tid*16] and [8192+tid*16]

    const int qBase = sg * 4096;    // this group's first quarter (byte offset)
    // per-lane fragment byte offsets (quarter-local; +512*ci for V groups)
    const int aK0o = 2 * frag_off(ln, q4 * 8);
    const int aK1o = 2 * frag_off(ln, 32 + q4 * 8);
    const int aVo  = 32 * ln + 2 * ((q4 ^ ((ln >> 2) & 3)) * 4);

    // Q fragments: rows 16ts+ln of each 64-t half (two strips, 4 x 16B loads)
    const unsigned short* qtile = ws + QP_OFF + (size_t)(h * 32 + qt * 2) * 4096;
    bf16x8 bQ[2][2];
    #pragma unroll
    for (int st = 0; st < 2; st++) {
        bQ[st][0] = *(const bf16x8*)(qtile + st * 4096 + frag_off(16 * ts + ln, q4 * 8));
        bQ[st][1] = *(const bf16x8*)(qtile + st * 4096 + frag_off(16 * ts + ln, 32 + q4 * 8));
    }

    const char* kvb = (const char*)ws + (size_t)(h * 32) * 16384 + tid * 16;
    STAGE(0, 0)                      // tiles 0,1 in flight (4 cps/thread)
    STAGE(1, 1)

    const f32x4 ZF = {0.f, 0.f, 0.f, 0.f};
    f32x4 acc_o[2][4];   // [strip][ci]: partial over this group's s-quarters
    #pragma unroll
    for (int st = 0; st < 2; st++)
        #pragma unroll
        for (int ci = 0; ci < 4; ci++) acc_o[st][ci] = ZF;
    float l_acc[2] = {0.f, 0.f};

    #pragma unroll 1
    for (int m = 0; m < 15; m++) {   // kt = 0..29
        BODY(2 * m,     0, 1, 0x0F72)   // vmcnt(2): tile KT landed
        BODY(2 * m + 1, 1, 1, 0x0F72)
    }
    BODY(30, 0, 0, 0x0F72)           // no stage; tile 31 still in flight
    BODY(31, 1, 0, 0x0F70)           // vmcnt(0)

    // ---- epilogue: 2-way s-merge (sg1 -> sg0 via LDS), direct store ----
    float lg[2];
    #pragma unroll
    for (int st = 0; st < 2; st++) { // l partial: reduce over q4 groups
        float s = l_acc[st];
        s += __shfl_xor(s, 16, 64);
        s += __shfl_xor(s, 32, 64);
        lg[st] = s;
    }
    __syncthreads();                 // all loop LDS reads done; sbuf reusable
    float* slots = (float*)sbuf;     // 8 regions x 4KB = (ts*2+st) x [ci][lane]
    if (sg == 1) {
        #pragma unroll
        for (int st = 0; st < 2; st++) {
            float* dst = slots + (ts * 2 + st) * 1024;
            #pragma unroll
            for (int ci = 0; ci < 4; ci++)
                *(f32x4*)(dst + ci * 256 + lane * 4) = acc_o[st][ci];
            if (q4 == 0) lmrg[(ts * 2 + st) * 16 + ln] = lg[st];
        }
    }
    __syncthreads();
    if (sg == 0) {
        #pragma unroll
        for (int st = 0; st < 2; st++) {
            const float* srcp = slots + (ts * 2 + st) * 1024;
            const float linv = 1.0f / (lg[st] + lmrg[(ts * 2 + st) * 16 + ln]);
            float* ob = out + (size_t)h * D * T + t0 + st * 64 + 16 * ts + ln;
            #pragma unroll
            for (int ci = 0; ci < 4; ci++) {
                f32x4 v = acc_o[st][ci] + *(const f32x4*)(srcp + ci * 256 + lane * 4);
                #pragma unroll
                for (int rr = 0; rr < 4; rr++)
                    ob[(size_t)(16 * ci + q4 * 4 + rr) * T] = v[rr] * linv;
            }
        }
    }
}

// ---------------- fallback (proven): used if ws too small --------------------
__device__ inline bf16x8 frag8(const unsigned short* p, int row, int c0) {
    return *(const bf16x8*)(p + frag_off(row, c0));
}

__global__ __launch_bounds__(256)
void attn_fallback(const float* __restrict__ qkv, float* __restrict__ out) {
    const int h     = blockIdx.y;
    const int t0    = blockIdx.x * 64;
    const int tid   = threadIdx.x;
    const int lane  = tid & 63;
    const int strip = tid >> 6;
    const int ln    = lane & 15;
    const int q4    = lane >> 4;

    __shared__ unsigned short Qs[64 * D];
    __shared__ unsigned short Ks[64 * D];
    __shared__ unsigned short Vs[D * 64];
    __shared__ unsigned short Pss[64 * 64];
    __shared__ float l_lds[64];

    const float* qb = qkv + (size_t)h * 3 * D * T;
    const float* kb = qb + (size_t)D * T;
    const float* vb = qb + (size_t)(2 * D) * T;
    const int s4 = tid & 15;
    const int c0 = (tid >> 4) * 4;
    {
        float fr[4][4];
        #pragma unroll
        for (int r = 0; r < 4; r++)
            *(f32x4*)fr[r] = *(const f32x4*)(qb + (size_t)(c0 + r) * T + t0 + s4 * 4);
        #pragma unroll
        for (int j = 0; j < 4; j++) {
            int trow = s4 * 4 + j;
            u16x4 wv = { f2bf(fr[0][j]), f2bf(fr[1][j]), f2bf(fr[2][j]), f2bf(fr[3][j]) };
            *(u16x4*)(Qs + frag_off(trow, c0) + (c0 & 7)) = wv;
        }
    }
    __syncthreads();
    const int arow = strip * 16 + ln;
    const int kg   = q4 * 8;
    const bf16x8 aq0 = frag8(Qs, arow, kg);
    const bf16x8 aq1 = frag8(Qs, arow, 32 + kg);
    f32x4 acc_o[4];
    #pragma unroll
    for (int m = 0; m < 4; m++) acc_o[m] = (f32x4){0.f, 0.f, 0.f, 0.f};
    float l_acc[4] = {0.f, 0.f, 0.f, 0.f};
    constexpr float S2 = 0.125f * 1.44269504088896340736f;
    for (int kt = 0; kt < NT; kt++) {
        const int s0 = kt * 64;
        float kr[4][4], vr[4][4];
        #pragma unroll
        for (int r = 0; r < 4; r++)
            *(f32x4*)kr[r] = *(const f32x4*)(kb + (size_t)(c0 + r) * T + s0 + s4 * 4);
        #pragma unroll
        for (int r = 0; r < 4; r++)
            *(f32x4*)vr[r] = *(const f32x4*)(vb + (size_t)(c0 + r) * T + s0 + s4 * 4);
        __syncthreads();
        #pragma unroll
        for (int j = 0; j < 4; j++) {
            int srow = s4 * 4 + j;
            u16x4 wk = { f2bf(kr[0][j]), f2bf(kr[1][j]), f2bf(kr[2][j]), f2bf(kr[3][j]) };
            *(u16x4*)(Ks + frag_off(srow, c0) + (c0 & 7)) = wk;
        }
        #pragma unroll
        for (int r = 0; r < 4; r++) {
            int row = c0 + r, cc = s4 * 4;
            u16x4 wv = { f2bf(vr[r][0]), f2bf(vr[r][1]), f2bf(vr[r][2]), f2bf(vr[r][3]) };
            *(u16x4*)(Vs + frag_off(row, cc) + (cc & 7)) = wv;
        }
        __syncthreads();
        f32x4 accs[4];
        #pragma unroll
        for (int ns = 0; ns < 4; ns++) {
            bf16x8 b0 = frag8(Ks, ns * 16 + ln, kg);
            bf16x8 b1 = frag8(Ks, ns * 16 + ln, 32 + kg);
            f32x4 z = {0.f, 0.f, 0.f, 0.f};
            z = __builtin_amdgcn_mfma_f32_16x16x32_bf16(aq0, b0, z, 0, 0, 0);
            z = __builtin_amdgcn_mfma_f32_16x16x32_bf16(aq1, b1, z, 0, 0, 0);
            accs[ns] = z;
        }
        #pragma unroll
        for (int ns = 0; ns < 4; ns++) {
            int scol = ns * 16 + ln;
            #pragma unroll
            for (int r = 0; r < 4; r++) {
                float p = __builtin_amdgcn_exp2f(accs[ns][r] * S2);
                l_acc[r] += p;
                int trow = strip * 16 + q4 * 4 + r;
                int g = ((scol >> 3) ^ ((trow >> 1) & 7));
                Pss[trow * 64 + g * 8 + (scol & 7)] = f2bf(p);
            }
        }
        bf16x8 bp0 = frag8(Pss, arow, kg);
        bf16x8 bp1 = frag8(Pss, arow, 32 + kg);
        #pragma unroll
        for (int ms = 0; ms < 4; ms++) {
            bf16x8 av0 = frag8(Vs, ms * 16 + ln, kg);
            bf16x8 av1 = frag8(Vs, ms * 16 + ln, 32 + kg);
            acc_o[ms] = __builtin_amdgcn_mfma_f32_16x16x32_bf16(av0, bp0, acc_o[ms], 0, 0, 0);
            acc_o[ms] = __builtin_amdgcn_mfma_f32_16x16x32_bf16(av1, bp1, acc_o[ms], 0, 0, 0);
        }
    }
    #pragma unroll
    for (int r = 0; r < 4; r++) {
        float s = l_acc[r];
        s += __shfl_xor(s, 1, 64);
        s += __shfl_xor(s, 2, 64);
        s += __shfl_xor(s, 4, 64);
        s += __shfl_xor(s, 8, 64);
        if (ln == 0) l_lds[strip * 16 + q4 * 4 + r] = s;
    }
    const float linv = 1.0f / l_lds[strip * 16 + ln];
    const int tg = t0 + strip * 16 + ln;
    float* ob = out + (size_t)h * D * T;
    #pragma unroll
    for (int ms = 0; ms < 4; ms++)
        #pragma unroll
        for (int r = 0; r < 4; r++) {
            int c = ms * 16 + q4 * 4 + r;
            ob[(size_t)c * T + tg] = acc_o[ms][r] * linv;
        }
}

} // namespace

extern "C" void kernel_launch(void* const* d_in, const int* in_sizes, int n_in,
                              void* d_out, int out_size, void* d_ws, size_t ws_size,
                              hipStream_t stream) {
    const float* qkv = (const float*)d_in[0];
    float* out = (float*)d_out;
    if (ws_size >= WS_NEED) {
        prepass<<<dim3(32, 64, 3), 256, 0, stream>>>(qkv, (unsigned short*)d_ws);
        attn_main<<<dim3(64, 16), 512, 0, stream>>>((const unsigned short*)d_ws, out);
    } else {
        attn_fallback<<<dim3(32, 64), 256, 0, stream>>>(qkv, out);
    }
}